// Round 11
// baseline (82.533 us; speedup 1.0000x reference)
//
#include <hip/hip_runtime.h>

// Problem constants (from reference)
#define B 8
#define C 64
#define H 64
#define W 64
#define K 5
#define PAD 2
#define HW (H * W)          // 4096
#define CHW (C * HW)        // 262144
#define TOT (B * CHW)       // 2097152

// attn tiling: block = 16 rows x 64 cols of one (b,c) plane
#define TROWS 16
#define SROWS (TROWS + 2 * PAD)   // 20 staged rows
#define SCOLS 72                  // 64 + 2*PAD, padded to 72 for 16B row alignment
#define NSLOT2 (SROWS * (SCOLS / 2))  // 720 float2 slots per plane

typedef __attribute__((ext_vector_type(8))) short short8;   // 8 bf16 = 4 VGPR
typedef __attribute__((ext_vector_type(4))) float f32x4;    // mfma accum

__device__ inline unsigned short f2bf(float f) {            // fp32 -> bf16 RNE
    unsigned u = __float_as_uint(f);
    u = u + 0x7fffu + ((u >> 16) & 1u);
    return (unsigned short)(u >> 16);
}
__device__ inline float bf2f(unsigned short h) {
    return __uint_as_float(((unsigned)h) << 16);
}

// ---------------------------------------------------------------------------
// Pass 1 (v7): qkv as MFMA GEMM with INLINE weight conversion (wprep folded
// in: each lane loads its A-fragment's 8 fp32 weights straight from Wq/Wk/Wv
// (2x float4, L2-hot 16 KB) and splits to bf16 hi/lo in registers — one
// fewer dispatch, no Whl round-trip).  Out[192,HW] = W[192,64] @ x[64,HW]
// per b; fp32 emulated as Wh*xh + Wh*xl + Wl*xh (Wl*xl ~2^-18 dropped).
// Block = (b, 32-col hw-chunk) = 1024 blocks.  Fragment maps (HW-verified):
// A lane: row=l&15, k=(l>>4)*8+j; B lane: col=l&15, same k; D: col=lane&15,
// row=(lane>>4)*4+reg.
// NOTE: this round the kernel is launched 5x (idempotent) as a timing
// decomposition probe — see kernel_launch.
// ---------------------------------------------------------------------------
__global__ __launch_bounds__(256) void qkv_mfma(
    const float* __restrict__ x,
    const float* __restrict__ Wq,
    const float* __restrict__ Wk,
    const float* __restrict__ Wv,
    float* __restrict__ qb, float* __restrict__ kb, float* __restrict__ vb)
{
    __shared__ unsigned short sxh[32][72];   // [n][k], 4.6 KB
    __shared__ unsigned short sxl[32][72];

    const int bid = blockIdx.x;
    const int b   = bid >> 7;            // 128 chunks per batch
    const int n0  = (bid & 127) * 32;    // hw base
    const int t   = threadIdx.x;

    // ---- stage + convert: 512 float4, 2 per thread, coalesced ----
    const float* xb = x + b * CHW;
#pragma unroll
    for (int i = 0; i < 2; ++i) {
        const int flat = t + i * 256;        // 0..511
        const int k    = flat >> 3;          // 8 float4 per k-row of 32
        const int n4   = (flat & 7) << 2;
        const float4 v = *(const float4*)(xb + k * HW + n0 + n4);
        const float vv[4] = {v.x, v.y, v.z, v.w};
#pragma unroll
        for (int j = 0; j < 4; ++j) {
            const unsigned short h = f2bf(vv[j]);
            sxh[n4 + j][k] = h;
            sxl[n4 + j][k] = f2bf(vv[j] - bf2f(h));
        }
    }
    __syncthreads();

    const int lane = t & 63;
    const int wv   = __builtin_amdgcn_readfirstlane(t >> 6);  // wave id 0..3
    const int lr   = lane & 15;          // tile row (A) / col (B,D)
    const int lk   = (lane >> 4) * 8;    // k-group base

    // ---- A fragments, converted inline from fp32 W ----
    short8 ah[3][2], al[3][2];
#pragma unroll
    for (int ot = 0; ot < 3; ++ot) {
        const int tile = wv * 3 + ot;            // 0..11
        const int m    = tile >> 2;              // 0=q,1=k,2=v
        const int ol0  = (tile & 3) * 16;        // o base within matrix
        const float* Wm = (m == 0) ? Wq : (m == 1) ? Wk : Wv;
        const float* wrow = Wm + (ol0 + lr) * 64;
#pragma unroll
        for (int ks = 0; ks < 2; ++ks) {
            const float4 w0 = *(const float4*)(wrow + lk + ks * 32);
            const float4 w1 = *(const float4*)(wrow + lk + ks * 32 + 4);
            const float wv8[8] = {w0.x, w0.y, w0.z, w0.w,
                                  w1.x, w1.y, w1.z, w1.w};
            short8 hi, lo;
#pragma unroll
            for (int j = 0; j < 8; ++j) {
                const unsigned short hh = f2bf(wv8[j]);
                hi[j] = (short)hh;
                lo[j] = (short)f2bf(wv8[j] - bf2f(hh));
            }
            ah[ot][ks] = hi;
            al[ot][ks] = lo;
        }
    }

    f32x4 acc[3][2];
#pragma unroll
    for (int ot = 0; ot < 3; ++ot)
#pragma unroll
        for (int nt = 0; nt < 2; ++nt) acc[ot][nt] = (f32x4)0.f;

#pragma unroll
    for (int nt = 0; nt < 2; ++nt) {
        const short8 bh0 = *(const short8*)&sxh[nt * 16 + lr][lk];
        const short8 bh1 = *(const short8*)&sxh[nt * 16 + lr][32 + lk];
        const short8 bl0 = *(const short8*)&sxl[nt * 16 + lr][lk];
        const short8 bl1 = *(const short8*)&sxl[nt * 16 + lr][32 + lk];
#pragma unroll
        for (int ot = 0; ot < 3; ++ot) {
            f32x4 d = acc[ot][nt];
            d = __builtin_amdgcn_mfma_f32_16x16x32_bf16(ah[ot][0], bh0, d, 0, 0, 0);
            d = __builtin_amdgcn_mfma_f32_16x16x32_bf16(ah[ot][1], bh1, d, 0, 0, 0);
            d = __builtin_amdgcn_mfma_f32_16x16x32_bf16(ah[ot][0], bl0, d, 0, 0, 0);
            d = __builtin_amdgcn_mfma_f32_16x16x32_bf16(ah[ot][1], bl1, d, 0, 0, 0);
            d = __builtin_amdgcn_mfma_f32_16x16x32_bf16(al[ot][0], bh0, d, 0, 0, 0);
            d = __builtin_amdgcn_mfma_f32_16x16x32_bf16(al[ot][1], bh1, d, 0, 0, 0);
            acc[ot][nt] = d;
        }
    }

    // ---- epilogue: D col=lane&15 (n), row=(lane>>4)*4+r (o) ----
#pragma unroll
    for (int ot = 0; ot < 3; ++ot) {
        const int tile = wv * 3 + ot;
        const int m    = tile >> 2;
        const int ol0  = (tile & 3) * 16;
        float* ob = (m == 0) ? qb : (m == 1) ? kb : vb;
        float* basep = ob + b * CHW + ol0 * HW + n0;
#pragma unroll
        for (int nt = 0; nt < 2; ++nt)
#pragma unroll
            for (int r = 0; r < 4; ++r) {
                const int orow = (lane >> 4) * 4 + r;
                basep[orow * HW + nt * 16 + lr] = acc[ot][nt][r];
            }
    }
}

// ---------------------------------------------------------------------------
// Pass 2: per-channel 5x5 windowed softmax attention, LDS-staged.
// (byte-identical to round-5 version — kept fixed for clean attribution)
// ---------------------------------------------------------------------------
__global__ __launch_bounds__(256) void attn_kernel(
    const float* __restrict__ qb,
    const float* __restrict__ kb,
    const float* __restrict__ vb,
    const float* __restrict__ rel_h,
    const float* __restrict__ rel_w,
    float* __restrict__ out)
{
    __shared__ __align__(16) float sk[SROWS][SCOLS];
    __shared__ __align__(16) float sv[SROWS][SCOLS];

    const int bid = blockIdx.x;
    const int pl  = bid >> 2;          // b*C + c
    const int h0  = (bid & 3) * TROWS;
    const int c   = pl & 63;
    const int t   = threadIdx.x;

    const float* kp = kb + pl * HW;
    const float* vp = vb + pl * HW;

    // ---- stage: 2 planes * 720 float2 slots ----
    for (int idx = t; idx < 2 * NSLOT2; idx += 256) {
        const int p   = (idx >= NSLOT2);
        const int rem = p ? idx - NSLOT2 : idx;
        const int row = rem / (SCOLS / 2);
        const int c2  = rem - row * (SCOLS / 2);   // float2 col 0..35
        const int g   = h0 + row - PAD;            // global row
        float2 val = make_float2(0.f, 0.f);
        if (((unsigned)g < (unsigned)H) & (c2 >= 1) & (c2 <= 32)) {
            const float* src = (p ? vp : kp) + g * W + (c2 * 2 - 2);
            val = *(const float2*)src;
        }
        float* dst = (p ? &sv[0][0] : &sk[0][0]) + row * SCOLS + c2 * 2;
        *(float2*)dst = val;
    }
    __syncthreads();

    // ---- compute: 1 quad (4 px) per thread ----
    const int lr = t >> 4;             // local row 0..15
    const int w0 = (t & 15) << 2;      // col base 0,4,..,60
    const int h  = h0 + lr;

    const float4 qv = *(const float4*)(qb + pl * HW + h * W + w0);
    const float qx[4] = {qv.x, qv.y, qv.z, qv.w};

    const bool is_h = (c < (C / 2));
    const float* rp = is_h ? (rel_h + c * K) : (rel_w + (c - C / 2) * K);
    float r[K];
#pragma unroll
    for (int u = 0; u < K; ++u) r[u] = rp[u];

    float den[4] = {0.f, 0.f, 0.f, 0.f};
    float num[4] = {0.f, 0.f, 0.f, 0.f};

    if (is_h) {
#pragma unroll
        for (int i = 0; i < K; ++i) {
            const float4 ka = *(const float4*)&sk[lr + i][w0];
            const float4 kc = *(const float4*)&sk[lr + i][w0 + 4];
            const float4 va = *(const float4*)&sv[lr + i][w0];
            const float4 vc = *(const float4*)&sv[lr + i][w0 + 4];
            const float kr[8] = {ka.x, ka.y, ka.z, ka.w, kc.x, kc.y, kc.z, kc.w};
            const float vr[8] = {va.x, va.y, va.z, va.w, vc.x, vc.y, vc.z, vc.w};
            float qri[4];
#pragma unroll
            for (int px = 0; px < 4; ++px) qri[px] = qx[px] * r[i];
#pragma unroll
            for (int j = 0; j < K; ++j) {
#pragma unroll
                for (int px = 0; px < 4; ++px) {
                    const float e = __expf(fmaf(qx[px], kr[px + j], qri[px]));
                    den[px] += e;
                    num[px] = fmaf(e, vr[px + j], num[px]);
                }
            }
        }
    } else {
        float qrj[4][K];
#pragma unroll
        for (int px = 0; px < 4; ++px)
#pragma unroll
            for (int j = 0; j < K; ++j) qrj[px][j] = qx[px] * r[j];
#pragma unroll
        for (int i = 0; i < K; ++i) {
            const float4 ka = *(const float4*)&sk[lr + i][w0];
            const float4 kc = *(const float4*)&sk[lr + i][w0 + 4];
            const float4 va = *(const float4*)&sv[lr + i][w0];
            const float4 vc = *(const float4*)&sv[lr + i][w0 + 4];
            const float kr[8] = {ka.x, ka.y, ka.z, ka.w, kc.x, kc.y, kc.z, kc.w};
            const float vr[8] = {va.x, va.y, va.z, va.w, vc.x, vc.y, vc.z, vc.w};
#pragma unroll
            for (int j = 0; j < K; ++j) {
#pragma unroll
                for (int px = 0; px < 4; ++px) {
                    const float e = __expf(fmaf(qx[px], kr[px + j], qrj[px][j]));
                    den[px] += e;
                    num[px] = fmaf(e, vr[px + j], num[px]);
                }
            }
        }
    }

    float4 o;
    o.x = num[0] * __builtin_amdgcn_rcpf(den[0]);
    o.y = num[1] * __builtin_amdgcn_rcpf(den[1]);
    o.z = num[2] * __builtin_amdgcn_rcpf(den[2]);
    o.w = num[3] * __builtin_amdgcn_rcpf(den[3]);
    *(float4*)(out + pl * HW + h * W + w0) = o;
}

// ---------------------------------------------------------------------------
// MEASUREMENT ROUND: qkv_mfma launched 5x (idempotent — identical writes).
// Delta vs round 10's 43.1 us isolates t_qkv: total ~= base + 4*t_qkv.
//   ~120 us -> t_qkv ~20 (kernel-real, attack qkv next)
//   ~60  us -> t_qkv ~5
//   ~46-50 us -> t_qkv ~1-2 -> attn and/or fixed replay overhead dominate
// ---------------------------------------------------------------------------
extern "C" void kernel_launch(void* const* d_in, const int* in_sizes, int n_in,
                              void* d_out, int out_size, void* d_ws, size_t ws_size,
                              hipStream_t stream)
{
    const float* x     = (const float*)d_in[0];
    const float* Wq    = (const float*)d_in[1];
    const float* Wk    = (const float*)d_in[2];
    const float* Wv    = (const float*)d_in[3];
    const float* rel_h = (const float*)d_in[4];
    const float* rel_w = (const float*)d_in[5];

    float* qb = (float*)d_ws;        // [B,C,64,64]  8 MB
    float* kb = qb + TOT;            // [B,C,64,64]  8 MB
    float* vb = kb + TOT;            // [B,C,64,64]  8 MB

    for (int rep = 0; rep < 5; ++rep)
        qkv_mfma<<<B * 128, 256, 0, stream>>>(x, Wq, Wk, Wv, qb, kb, vb);

    attn_kernel<<<B * C * 4, 256, 0, stream>>>(qb, kb, vb, rel_h, rel_w,
                                               (float*)d_out);
}

// Round 12
// 32.220 us; speedup vs baseline: 2.5615x; 2.5615x over previous
//
#include <hip/hip_runtime.h>

// Problem constants (from reference)
#define B 8
#define C 64
#define H 64
#define W 64
#define K 5
#define PAD 2
#define HW (H * W)          // 4096
#define CHW (C * HW)        // 262144
#define TOT (B * CHW)       // 2097152

// attn tiling: block = 16 rows x 64 cols of one (b,c) plane
#define TROWS 16
#define SROWS (TROWS + 2 * PAD)   // 20 staged rows
#define SCOLS 72                  // 64 + 2*PAD, padded to 72 for 16B row alignment
#define NSLOT2 (SROWS * (SCOLS / 2))  // 720 float2 slots per plane

typedef __attribute__((ext_vector_type(8))) short short8;   // 8 bf16 = 4 VGPR
typedef __attribute__((ext_vector_type(4))) float f32x4;    // mfma accum

__device__ inline unsigned short f2bf(float f) {            // fp32 -> bf16 RNE
    unsigned u = __float_as_uint(f);
    u = u + 0x7fffu + ((u >> 16) & 1u);
    return (unsigned short)(u >> 16);
}
__device__ inline float bf2f(unsigned short h) {
    return __uint_as_float(((unsigned)h) << 16);
}

// ---------------------------------------------------------------------------
// Pass 1 (v8): qkv MFMA GEMM, XCD-swizzled grid.
// bid = chunk*8 + b  ->  bid%8 = b = XCD id (round-robin dispatch model):
// ALL blocks of batch b run on XCD b, so q/k/v for batch b (3 MB) are
// written into XCD-b's private L2 (4 MB) — and the attn kernel (same
// swizzle) reads them back from the SAME L2 instead of cross-XCD fabric.
// Rest identical to r11: inline W->bf16 hi/lo split, Wh*xh+Wh*xl+Wl*xh,
// block = (b, 32-col hw-chunk), fragment maps HW-verified.
// ---------------------------------------------------------------------------
__global__ __launch_bounds__(256) void qkv_mfma(
    const float* __restrict__ x,
    const float* __restrict__ Wq,
    const float* __restrict__ Wk,
    const float* __restrict__ Wv,
    float* __restrict__ qb, float* __restrict__ kb, float* __restrict__ vb)
{
    __shared__ unsigned short sxh[32][72];   // [n][k], 4.6 KB
    __shared__ unsigned short sxl[32][72];

    const int bid = blockIdx.x;
    const int b   = bid & 7;             // XCD co-residency: batch = XCD
    const int n0  = (bid >> 3) * 32;     // hw base (128 chunks per batch)
    const int t   = threadIdx.x;

    // ---- stage + convert: 512 float4, 2 per thread, coalesced ----
    const float* xb = x + b * CHW;
#pragma unroll
    for (int i = 0; i < 2; ++i) {
        const int flat = t + i * 256;        // 0..511
        const int k    = flat >> 3;          // 8 float4 per k-row of 32
        const int n4   = (flat & 7) << 2;
        const float4 v = *(const float4*)(xb + k * HW + n0 + n4);
        const float vv[4] = {v.x, v.y, v.z, v.w};
#pragma unroll
        for (int j = 0; j < 4; ++j) {
            const unsigned short h = f2bf(vv[j]);
            sxh[n4 + j][k] = h;
            sxl[n4 + j][k] = f2bf(vv[j] - bf2f(h));
        }
    }
    __syncthreads();

    const int lane = t & 63;
    const int wv   = __builtin_amdgcn_readfirstlane(t >> 6);  // wave id 0..3
    const int lr   = lane & 15;          // tile row (A) / col (B,D)
    const int lk   = (lane >> 4) * 8;    // k-group base

    // ---- A fragments, converted inline from fp32 W ----
    short8 ah[3][2], al[3][2];
#pragma unroll
    for (int ot = 0; ot < 3; ++ot) {
        const int tile = wv * 3 + ot;            // 0..11
        const int m    = tile >> 2;              // 0=q,1=k,2=v
        const int ol0  = (tile & 3) * 16;        // o base within matrix
        const float* Wm = (m == 0) ? Wq : (m == 1) ? Wk : Wv;
        const float* wrow = Wm + (ol0 + lr) * 64;
#pragma unroll
        for (int ks = 0; ks < 2; ++ks) {
            const float4 w0 = *(const float4*)(wrow + lk + ks * 32);
            const float4 w1 = *(const float4*)(wrow + lk + ks * 32 + 4);
            const float wv8[8] = {w0.x, w0.y, w0.z, w0.w,
                                  w1.x, w1.y, w1.z, w1.w};
            short8 hi, lo;
#pragma unroll
            for (int j = 0; j < 8; ++j) {
                const unsigned short hh = f2bf(wv8[j]);
                hi[j] = (short)hh;
                lo[j] = (short)f2bf(wv8[j] - bf2f(hh));
            }
            ah[ot][ks] = hi;
            al[ot][ks] = lo;
        }
    }

    f32x4 acc[3][2];
#pragma unroll
    for (int ot = 0; ot < 3; ++ot)
#pragma unroll
        for (int nt = 0; nt < 2; ++nt) acc[ot][nt] = (f32x4)0.f;

#pragma unroll
    for (int nt = 0; nt < 2; ++nt) {
        const short8 bh0 = *(const short8*)&sxh[nt * 16 + lr][lk];
        const short8 bh1 = *(const short8*)&sxh[nt * 16 + lr][32 + lk];
        const short8 bl0 = *(const short8*)&sxl[nt * 16 + lr][lk];
        const short8 bl1 = *(const short8*)&sxl[nt * 16 + lr][32 + lk];
#pragma unroll
        for (int ot = 0; ot < 3; ++ot) {
            f32x4 d = acc[ot][nt];
            d = __builtin_amdgcn_mfma_f32_16x16x32_bf16(ah[ot][0], bh0, d, 0, 0, 0);
            d = __builtin_amdgcn_mfma_f32_16x16x32_bf16(ah[ot][1], bh1, d, 0, 0, 0);
            d = __builtin_amdgcn_mfma_f32_16x16x32_bf16(ah[ot][0], bl0, d, 0, 0, 0);
            d = __builtin_amdgcn_mfma_f32_16x16x32_bf16(ah[ot][1], bl1, d, 0, 0, 0);
            d = __builtin_amdgcn_mfma_f32_16x16x32_bf16(al[ot][0], bh0, d, 0, 0, 0);
            d = __builtin_amdgcn_mfma_f32_16x16x32_bf16(al[ot][1], bh1, d, 0, 0, 0);
            acc[ot][nt] = d;
        }
    }

    // ---- epilogue: D col=lane&15 (n), row=(lane>>4)*4+r (o) ----
#pragma unroll
    for (int ot = 0; ot < 3; ++ot) {
        const int tile = wv * 3 + ot;
        const int m    = tile >> 2;
        const int ol0  = (tile & 3) * 16;
        float* ob = (m == 0) ? qb : (m == 1) ? kb : vb;
        float* basep = ob + b * CHW + ol0 * HW + n0;
#pragma unroll
        for (int nt = 0; nt < 2; ++nt)
#pragma unroll
            for (int r = 0; r < 4; ++r) {
                const int orow = (lane >> 4) * 4 + r;
                basep[orow * HW + nt * 16 + lr] = acc[ot][nt][r];
            }
    }
}

// ---------------------------------------------------------------------------
// Pass 2: per-channel 5x5 windowed softmax attention, LDS-staged,
// XCD-swizzled grid: bid = u*8 + b (u = chan*4 + rowtile), so every block
// of batch b runs on XCD b and reads q/k/v from the same per-XCD L2 that
// qkv_mfma just wrote.  Compute body byte-identical to round-5.
// ---------------------------------------------------------------------------
__global__ __launch_bounds__(256) void attn_kernel(
    const float* __restrict__ qb,
    const float* __restrict__ kb,
    const float* __restrict__ vb,
    const float* __restrict__ rel_h,
    const float* __restrict__ rel_w,
    float* __restrict__ out)
{
    __shared__ __align__(16) float sk[SROWS][SCOLS];
    __shared__ __align__(16) float sv[SROWS][SCOLS];

    const int bid = blockIdx.x;
    const int b   = bid & 7;           // XCD co-residency: batch = XCD
    const int u   = bid >> 3;          // 0..255: chan*4 + rowtile
    const int c   = u >> 2;
    const int pl  = b * C + c;
    const int h0  = (u & 3) * TROWS;
    const int t   = threadIdx.x;

    const float* kp = kb + pl * HW;
    const float* vp = vb + pl * HW;

    // ---- stage: 2 planes * 720 float2 slots ----
    for (int idx = t; idx < 2 * NSLOT2; idx += 256) {
        const int p   = (idx >= NSLOT2);
        const int rem = p ? idx - NSLOT2 : idx;
        const int row = rem / (SCOLS / 2);
        const int c2  = rem - row * (SCOLS / 2);   // float2 col 0..35
        const int g   = h0 + row - PAD;            // global row
        float2 val = make_float2(0.f, 0.f);
        if (((unsigned)g < (unsigned)H) & (c2 >= 1) & (c2 <= 32)) {
            const float* src = (p ? vp : kp) + g * W + (c2 * 2 - 2);
            val = *(const float2*)src;
        }
        float* dst = (p ? &sv[0][0] : &sk[0][0]) + row * SCOLS + c2 * 2;
        *(float2*)dst = val;
    }
    __syncthreads();

    // ---- compute: 1 quad (4 px) per thread ----
    const int lr = t >> 4;             // local row 0..15
    const int w0 = (t & 15) << 2;      // col base 0,4,..,60
    const int h  = h0 + lr;

    const float4 qv = *(const float4*)(qb + pl * HW + h * W + w0);
    const float qx[4] = {qv.x, qv.y, qv.z, qv.w};

    const bool is_h = (c < (C / 2));
    const float* rp = is_h ? (rel_h + c * K) : (rel_w + (c - C / 2) * K);
    float r[K];
#pragma unroll
    for (int u2 = 0; u2 < K; ++u2) r[u2] = rp[u2];

    float den[4] = {0.f, 0.f, 0.f, 0.f};
    float num[4] = {0.f, 0.f, 0.f, 0.f};

    if (is_h) {
#pragma unroll
        for (int i = 0; i < K; ++i) {
            const float4 ka = *(const float4*)&sk[lr + i][w0];
            const float4 kc = *(const float4*)&sk[lr + i][w0 + 4];
            const float4 va = *(const float4*)&sv[lr + i][w0];
            const float4 vc = *(const float4*)&sv[lr + i][w0 + 4];
            const float kr[8] = {ka.x, ka.y, ka.z, ka.w, kc.x, kc.y, kc.z, kc.w};
            const float vr[8] = {va.x, va.y, va.z, va.w, vc.x, vc.y, vc.z, vc.w};
            float qri[4];
#pragma unroll
            for (int px = 0; px < 4; ++px) qri[px] = qx[px] * r[i];
#pragma unroll
            for (int j = 0; j < K; ++j) {
#pragma unroll
                for (int px = 0; px < 4; ++px) {
                    const float e = __expf(fmaf(qx[px], kr[px + j], qri[px]));
                    den[px] += e;
                    num[px] = fmaf(e, vr[px + j], num[px]);
                }
            }
        }
    } else {
        float qrj[4][K];
#pragma unroll
        for (int px = 0; px < 4; ++px)
#pragma unroll
            for (int j = 0; j < K; ++j) qrj[px][j] = qx[px] * r[j];
#pragma unroll
        for (int i = 0; i < K; ++i) {
            const float4 ka = *(const float4*)&sk[lr + i][w0];
            const float4 kc = *(const float4*)&sk[lr + i][w0 + 4];
            const float4 va = *(const float4*)&sv[lr + i][w0];
            const float4 vc = *(const float4*)&sv[lr + i][w0 + 4];
            const float kr[8] = {ka.x, ka.y, ka.z, ka.w, kc.x, kc.y, kc.z, kc.w};
            const float vr[8] = {va.x, va.y, va.z, va.w, vc.x, vc.y, vc.z, vc.w};
#pragma unroll
            for (int j = 0; j < K; ++j) {
#pragma unroll
                for (int px = 0; px < 4; ++px) {
                    const float e = __expf(fmaf(qx[px], kr[px + j], qrj[px][j]));
                    den[px] += e;
                    num[px] = fmaf(e, vr[px + j], num[px]);
                }
            }
        }
    }

    float4 o;
    o.x = num[0] * __builtin_amdgcn_rcpf(den[0]);
    o.y = num[1] * __builtin_amdgcn_rcpf(den[1]);
    o.z = num[2] * __builtin_amdgcn_rcpf(den[2]);
    o.w = num[3] * __builtin_amdgcn_rcpf(den[3]);
    *(float4*)(out + pl * HW + h * W + w0) = o;
}

// ---------------------------------------------------------------------------
extern "C" void kernel_launch(void* const* d_in, const int* in_sizes, int n_in,
                              void* d_out, int out_size, void* d_ws, size_t ws_size,
                              hipStream_t stream)
{
    const float* x     = (const float*)d_in[0];
    const float* Wq    = (const float*)d_in[1];
    const float* Wk    = (const float*)d_in[2];
    const float* Wv    = (const float*)d_in[3];
    const float* rel_h = (const float*)d_in[4];
    const float* rel_w = (const float*)d_in[5];

    float* qb = (float*)d_ws;        // [B,C,64,64]  8 MB
    float* kb = qb + TOT;            // [B,C,64,64]  8 MB
    float* vb = kb + TOT;            // [B,C,64,64]  8 MB

    qkv_mfma<<<B * 128, 256, 0, stream>>>(x, Wq, Wk, Wv, qb, kb, vb);

    attn_kernel<<<B * C * 4, 256, 0, stream>>>(qb, kb, vb, rel_h, rel_w,
                                               (float*)d_out);
}